// Round 15
// baseline (840.452 us; speedup 1.0000x reference)
//
#include <hip/hip_runtime.h>
#include <stdint.h>

#define H   32
#define ND  64
#define ED  16
#define MH  128
#define HH  1024   // H*H

__device__ __forceinline__ float bf2f(uint16_t u) {
    union { uint32_t u; float f; } v; v.u = ((uint32_t)u) << 16; return v.f;
}
__device__ __forceinline__ uint16_t f2bf(float f) {
    union { float f; uint32_t u; } v; v.f = f;
    return (uint16_t)((v.u + 0x7FFFu + ((v.u >> 16) & 1u)) >> 16);  // RNE
}
__device__ __forceinline__ float ldf(const void* p, size_t i, int isf32) {
    return isf32 ? ((const float*)p)[i] : bf2f(((const uint16_t*)p)[i]);
}

// ---- K-1: runtime dtype probes -------------------------------------------
__global__ void k_detect(const uint16_t* __restrict__ xr,
                         const int* __restrict__ ei, int nedges,
                         int* __restrict__ flags) {
    __shared__ int s_bad, s_hi;
    int t = threadIdx.x;
    if (t == 0) { s_bad = 0; s_hi = 0; }
    __syncthreads();
    int bad = 0;
    for (int i = t; i < 2048; i += 256) {
        uint16_t u = xr[i];
        int e = (u >> 7) & 0xFF;
        if (!(u == 0 || (e >= 96 && e <= 144))) bad++;
    }
    atomicAdd(&s_bad, bad);
    int mm = nedges < 4096 ? nedges : 4096;
    int hi = 0;
    for (int i = t; i < mm; i += 256) hi |= (ei[2 * i + 1] != 0);
    if (hi) atomicOr(&s_hi, 1);
    __syncthreads();
    if (t == 0) {
        flags[0] = (s_bad > 204) ? 1 : 0;   // fp32 inputs
        flags[1] = (s_hi == 0) ? 1 : 0;     // int64 edge_index
    }
}

__device__ __forceinline__ int load_idx(const int* __restrict__ ei, int is64,
                                        long long pos, int nnodes) {
    int v = is64 ? (int)(((const long long*)ei)[pos]) : ei[pos];
    v = v < 0 ? 0 : v;
    return v >= nnodes ? nnodes - 1 : v;
}

// ---- CSR-by-src build ----------------------------------------------------
__global__ void k_hist(const int* __restrict__ ei, const int* __restrict__ flags,
                       int* __restrict__ deg, int nedges, int nnodes) {
    int e = blockIdx.x * 256 + threadIdx.x;
    if (e >= nedges) return;
    int s = load_idx(ei, flags[1], e, nnodes);
    atomicAdd(&deg[s], 1);
}

__global__ void k_scan(const int* __restrict__ deg, int* __restrict__ cursor,
                       int nnodes) {
    __shared__ int tot[256];
    int t = threadIdx.x;
    int C = (nnodes + 255) >> 8;
    int b = t * C, e = b + C < nnodes ? b + C : nnodes;
    int s = 0;
    for (int i = b; i < e; i++) s += deg[i];
    tot[t] = s;
    __syncthreads();
    if (t == 0) {
        int acc = 0;
        for (int i = 0; i < 256; i++) { int v = tot[i]; tot[i] = acc; acc += v; }
    }
    __syncthreads();
    int acc = tot[t];
    for (int i = b; i < e; i++) { cursor[i] = acc; acc += deg[i]; }
}

__global__ void k_scatter(const int* __restrict__ ei, const int* __restrict__ flags,
                          int* __restrict__ cursor, int* __restrict__ perm,
                          int nedges, int nnodes) {
    int e = blockIdx.x * 256 + threadIdx.x;
    if (e >= nedges) return;
    int s = load_idx(ei, flags[1], e, nnodes);
    int p = atomicAdd(&cursor[s], 1);
    perm[p] = e;
}

// ---- K1: h0 = x @ Wp + bp  (+ fused u0 when emit_u) ----------------------
__global__ __launch_bounds__(256) void k_node_proj(
    const void* __restrict__ x, const void* __restrict__ wp,
    const void* __restrict__ bp, const void* __restrict__ b2g,
    float* __restrict__ h, float* __restrict__ u0, int nnodes,
    int emit_u, const int* __restrict__ flags)
{
    __shared__ float wp_s[ND][H];
    __shared__ float x_s[8][ND + 1];
    __shared__ float hn_s[8][33];
    __shared__ float b2_s[32 * 33];
    int isf32 = flags[0];
    int t = threadIdx.x;
    for (int i = t; i < ND * H; i += 256) wp_s[i >> 5][i & 31] = ldf(wp, i, isf32);
    for (int i = t; i < 8 * ND; i += 256) {
        int row = i >> 6, col = i & 63;
        int gn = blockIdx.x * 8 + row;
        x_s[row][col] = (gn < nnodes) ? ldf(x, (size_t)gn * ND + col, isf32) : 0.f;
    }
    if (emit_u)
        for (int i = t; i < 1024; i += 256)
            b2_s[(i >> 5) * 33 + (i & 31)] = ldf(b2g, i, isf32);
    __syncthreads();
    int nl = t >> 5, c = t & 31;
    int n = blockIdx.x * 8 + nl;
    int act = (n < nnodes);
    if (act) {
        float acc = ldf(bp, c, isf32);
#pragma unroll
        for (int k = 0; k < ND; k++) acc += x_s[nl][k] * wp_s[k][c];
        h[(size_t)n * H + c] = acc;
        hn_s[nl][c] = acc;
    }
    if (emit_u) {
        __syncthreads();
        if (act) {
            float au = 0.f;
#pragma unroll
            for (int j = 0; j < 32; j++) au += b2_s[c * 33 + j] * hn_s[nl][j];
            u0[(size_t)n * 32 + c] = au;
        }
    }
}

// ---- one-time: B'[j][i*128+k] = W2[k][i*32+j]  (512 KB fp32) -------------
__global__ void k_permw2(const void* __restrict__ w2g, float* __restrict__ Bp,
                         const int* __restrict__ flags) {
    int isf32 = flags[0];
    int idx = blockIdx.x * 256 + threadIdx.x;
    if (idx >= MH * HH) return;
    int k = idx / HH, col = idx % HH;   // col = i*32 + j
    int i = col >> 5, j = col & 31;
    Bp[(size_t)j * 4096 + i * 128 + k] = ldf(w2g, idx, isf32);
}

// ---- HI: k_T6 — skinny GEMM T = h @ B', 128-node tile, 2 blocks/CU -------
// (R14 verbatim — measured below top-5 cutoff; do not touch)
__global__ __launch_bounds__(256) void k_T6(
    const float* __restrict__ Bp, const float* __restrict__ h,
    float* __restrict__ Tall, int nnodes)
{
    __shared__ float h_s[128 * 33];        // 16.9 KB
    __shared__ float occ_pad[12288];       // 48 KB: occupancy governor
    int t = threadIdx.x;
    int cbq = blockIdx.x & 7;
    int n0 = (blockIdx.x >> 3) * 128;
    int c = cbq * 512 + t * 2;

    if (nnodes < 0) occ_pad[t] = h[t];     // never true: keeps pad allocated

    for (int i = t; i < 128 * 32; i += 256) {
        int n = i >> 5, j = i & 31;
        h_s[n * 33 + j] = (n0 + n < nnodes) ? h[(size_t)(n0 + n) * H + j] : 0.f;
    }
    float2 Breg[32];
#pragma unroll
    for (int j = 0; j < 32; j++)
        Breg[j] = *((const float2*)&Bp[(size_t)j * 4096 + c]);
    __syncthreads();

    int nmax = nnodes - n0; if (nmax > 128) nmax = 128;
    int n = 0;
    for (; n + 2 <= nmax; n += 2) {
        float2 a0 = {0.f, 0.f}, a1 = {0.f, 0.f};
#pragma unroll
        for (int j = 0; j < 32; j++) {
            float h0 = h_s[n * 33 + j], h1 = h_s[(n + 1) * 33 + j];
            float2 b = Breg[j];
            a0.x += h0 * b.x; a0.y += h0 * b.y;
            a1.x += h1 * b.x; a1.y += h1 * b.y;
        }
        *((float2*)&Tall[(size_t)(n0 + n) * 4096 + c]) = a0;
        *((float2*)&Tall[(size_t)(n0 + n + 1) * 4096 + c]) = a1;
    }
    if (n < nmax) {
        float2 a0 = {0.f, 0.f};
#pragma unroll
        for (int j = 0; j < 32; j++) {
            float h0 = h_s[n * 33 + j];
            float2 b = Breg[j];
            a0.x += h0 * b.x; a0.y += h0 * b.y;
        }
        *((float2*)&Tall[(size_t)(n0 + n) * 4096 + c]) = a0;
    }
}

// ---- HI: k_edge6 — 2 src-nodes/block; contiguous perm range --------------
// CSR rows of nodes 2b,2b+1 are contiguous; per-edge sel bit picks T/u set.
// T_lds sel offset = 4224 floats (≡0 mod 32 banks): mixed-sel reads 2-way max.
__global__ __launch_bounds__(256) void k_edge6(
    const void* __restrict__ ea, const void* __restrict__ w1,
    const void* __restrict__ b1g, const float* __restrict__ Tall,
    const float* __restrict__ u, const int* __restrict__ ei,
    const int* __restrict__ perm, const int* __restrict__ degp,
    const int* __restrict__ rendp, const int* __restrict__ flags,
    float* __restrict__ agg, int nedges, int nnodes)
{
    int nA = blockIdx.x * 2;
    int hasB = (nA + 1 < nnodes);
    int endA = rendp[nA], degA = degp[nA];
    int start = endA - degA;
    int endB = hasB ? rendp[nA + 1] : endA;
    int total = endB - start;
    if (total == 0) return;

    __shared__ float T_lds[2 * 4224];    // 33792 B (stride 132/row)
    __shared__ float hid_s[16 * 132];    //  8448 B
    __shared__ float w1_s[ED * MH];      //  8192 B
    __shared__ float ea_f[16 * ED];      //  1024 B
    __shared__ float b1_s[MH];
    __shared__ float u_lds[64];
    __shared__ int   e_s[16], d_s[16], src_s[16];

    int t = threadIdx.x;
    int isf32 = flags[0], is64 = flags[1];

    for (int f = t; f < 2048; f += 256) {
        int sel = f >> 10, fi = f & 1023;
        int node = nA + sel;
        if (node < nnodes) {
            float4 q = *((const float4*)&Tall[(size_t)node * 4096 + fi * 4]);
            int i = fi >> 5, k4 = (fi & 31) * 4;
            *((float4*)&T_lds[sel * 4224 + i * 132 + k4]) = q;
        }
    }
    for (int i = t; i < ED * MH; i += 256) w1_s[i] = ldf(w1, i, isf32);
    if (t < MH) b1_s[t] = ldf(b1g, t, isf32);
    if (t < 64) {
        int node = nA + (t >> 5);
        u_lds[t] = (node < nnodes) ? u[(size_t)node * 32 + (t & 31)] : 0.f;
    }

    int e_rel = t & 15, i2 = t >> 4;
    int nchunks = (total + 15) >> 4;

    for (int ch = 0; ch < nchunks; ch++) {
        __syncthreads();
        if (t < 16) {
            int idx = ch * 16 + t;
            int p = start + idx;
            int valid = (idx < total);
            int e = valid ? perm[p] : -1;
            e_s[t] = e;
            src_s[t] = (valid && p >= endA) ? 1 : 0;
            d_s[t] = (e >= 0) ? load_idx(ei, is64, (long long)nedges + e, nnodes) : 0;
        }
        __syncthreads();
        for (int i = t; i < 16 * ED; i += 256) {
            int e = e_s[i >> 4];
            ea_f[i] = (e >= 0) ? ldf(ea, (size_t)e * ED + (i & 15), isf32) : 0.f;
        }
        __syncthreads();
        // stage 1: hid = relu(ea @ W1 + b1)  (edge4-verbatim inner loop)
        for (int idx = t; idx < 16 * MH; idx += 256) {
            int el = idx >> 7, c = idx & 127;
            float acc = b1_s[c];
#pragma unroll
            for (int k = 0; k < ED; k++)
                acc += ea_f[el * ED + k] * w1_s[k * MH + c];
            hid_s[el * 132 + c] = fmaxf(acc, 0.f);
        }
        __syncthreads();
        if (e_s[e_rel] >= 0) {
            int sel = src_s[e_rel];
            int tb = sel * 4224;
            float a0 = u_lds[sel * 32 + i2], a1 = u_lds[sel * 32 + i2 + 16];
#pragma unroll
            for (int k4 = 0; k4 < 32; k4++) {
                float4 hv = *((const float4*)&hid_s[e_rel * 132 + k4 * 4]);
                float4 t0 = *((const float4*)&T_lds[tb + i2 * 132 + k4 * 4]);
                float4 t1 = *((const float4*)&T_lds[tb + (i2 + 16) * 132 + k4 * 4]);
                a0 += hv.x * t0.x + hv.y * t0.y + hv.z * t0.z + hv.w * t0.w;
                a1 += hv.x * t1.x + hv.y * t1.y + hv.z * t1.z + hv.w * t1.w;
            }
            int d = d_s[e_rel];
            atomicAdd(&agg[(size_t)d * H + i2], a0);
            atomicAdd(&agg[(size_t)d * H + i2 + 16], a1);
        }
    }
}

// ---- LO tier: R5's known-good direct VALU message kernel -----------------
__global__ __launch_bounds__(256) void k_msg_valu(
    const void* __restrict__ ea, const void* __restrict__ w1,
    const void* __restrict__ b1g, const void* __restrict__ w2g,
    const void* __restrict__ b2g, const float* __restrict__ h,
    const int* __restrict__ ei, const int* __restrict__ flags,
    float* __restrict__ agg, int nedges, int nnodes)
{
    __shared__ float hid_s[64 * 130];
    __shared__ float w1_s[ED * MH];
    __shared__ float b1_s[MH];
    __shared__ float ea_f[64 * ED];

    int t = threadIdx.x;
    int e0 = blockIdx.x * 64;
    int isf32 = flags[0], is64 = flags[1];

    for (int i = t; i < 64 * ED; i += 256) {
        int e = e0 + (i >> 4);
        ea_f[i] = (e < nedges) ? ldf(ea, (size_t)e * ED + (i & 15), isf32) : 0.f;
    }
    for (int i = t; i < ED * MH; i += 256) w1_s[i] = ldf(w1, i, isf32);
    for (int i = t; i < MH; i += 256) b1_s[i] = ldf(b1g, i, isf32);
    __syncthreads();

    for (int idx = t; idx < 64 * MH; idx += 256) {
        int el = idx >> 7, c = idx & 127;
        float acc = b1_s[c];
#pragma unroll
        for (int k = 0; k < ED; k++)
            acc += ea_f[el * ED + k] * w1_s[k * MH + c];
        hid_s[el * 130 + c] = fmaxf(acc, 0.f);
    }
    __syncthreads();

    int lane = t & 63, w = t >> 6;
    int b = w * 64 + lane;
    int j = b & 31;
    int q = b >> 5;

    float b2v[4];
#pragma unroll
    for (int m = 0; m < 4; m++) b2v[m] = ldf(b2g, b + 256 * m, isf32);

    for (int g = 0; g < 4; g++) {
        float acc[16][4];
#pragma unroll
        for (int e = 0; e < 16; e++)
#pragma unroll
            for (int m = 0; m < 4; m++) acc[e][m] = 0.f;

        for (int k2 = 0; k2 < 64; k2++) {
            float w2a[4], w2b[4];
#pragma unroll
            for (int m = 0; m < 4; m++) {
                w2a[m] = ldf(w2g, (size_t)(2 * k2) * HH + b + 256 * m, isf32);
                w2b[m] = ldf(w2g, (size_t)(2 * k2 + 1) * HH + b + 256 * m, isf32);
            }
#pragma unroll
            for (int e = 0; e < 16; e++) {
                float2 hv = *((const float2*)&hid_s[(g * 16 + e) * 130 + 2 * k2]);
#pragma unroll
                for (int m = 0; m < 4; m++)
                    acc[e][m] += hv.x * w2a[m] + hv.y * w2b[m];
            }
        }

#pragma unroll
        for (int e = 0; e < 16; e++) {
            int eg = e0 + g * 16 + e;
            int valid = (eg < nedges);
            int se = valid ? load_idx(ei, is64, eg, nnodes) : 0;
            float he = h[(size_t)se * H + j];
            int d = valid ? load_idx(ei, is64, (long long)nedges + eg, nnodes) : 0;
#pragma unroll
            for (int m = 0; m < 4; m++) {
                float p = (acc[e][m] + b2v[m]) * he;
                p += __shfl_xor(p, 1);
                p += __shfl_xor(p, 2);
                p += __shfl_xor(p, 4);
                p += __shfl_xor(p, 8);
                p += __shfl_xor(p, 16);
                if ((lane & 31) == 0 && valid)
                    atomicAdd(&agg[(size_t)d * H + (q + 8 * m)], p);
            }
        }
    }
}

// ---- K3: GRU cell; zeroes hin (next agg); fused u_next when emit_u -------
__global__ __launch_bounds__(256) void k_gru(
    const float* __restrict__ agg, float* hin,
    const void* __restrict__ w_ih, const void* __restrict__ w_hh,
    const void* __restrict__ b_ih, const void* __restrict__ b_hh,
    const void* __restrict__ b2g, float* __restrict__ u_next,
    float* __restrict__ hout, void* __restrict__ out_any,
    int nnodes, int finalstep, int emit_u, const int* __restrict__ flags)
{
    __shared__ float wih_s[3 * H][H + 1];
    __shared__ float whh_s[3 * H][H + 1];
    __shared__ float bih_s[3 * H], bhh_s[3 * H];
    __shared__ float a_s[8][H + 1], h_s[8][H + 1], hn_s[8][33];
    __shared__ float b2_s[32 * 33];
    int isf32 = flags[0];
    int t = threadIdx.x;
    for (int i = t; i < 3 * H * H; i += 256) {
        wih_s[i >> 5][i & 31] = ldf(w_ih, i, isf32);
        whh_s[i >> 5][i & 31] = ldf(w_hh, i, isf32);
    }
    for (int i = t; i < 3 * H; i += 256) {
        bih_s[i] = ldf(b_ih, i, isf32);
        bhh_s[i] = ldf(b_hh, i, isf32);
    }
    if (emit_u && !finalstep)
        for (int i = t; i < 1024; i += 256)
            b2_s[(i >> 5) * 33 + (i & 31)] = ldf(b2g, i, isf32);
    int nl = t >> 5, i = t & 31;
    int n = blockIdx.x * 8 + nl;
    int act = (n < nnodes);
    if (act) {
        a_s[nl][i] = agg[(size_t)n * H + i];
        h_s[nl][i] = hin[(size_t)n * H + i];
    }
    __syncthreads();

    if (act) {
        float gr = bih_s[i], gz = bih_s[H + i], gn = bih_s[2 * H + i];
        float hr = bhh_s[i], hz = bhh_s[H + i], hn = bhh_s[2 * H + i];
#pragma unroll
        for (int jj = 0; jj < H; jj++) {
            float a = a_s[nl][jj], hh = h_s[nl][jj];
            gr += a * wih_s[i][jj];      gz += a * wih_s[H + i][jj];  gn += a * wih_s[2 * H + i][jj];
            hr += hh * whh_s[i][jj];     hz += hh * whh_s[H + i][jj]; hn += hh * whh_s[2 * H + i][jj];
        }
        float r  = 1.f / (1.f + __expf(-(gr + hr)));
        float z  = 1.f / (1.f + __expf(-(gz + hz)));
        float nv = tanhf(gn + r * hn);
        float hnew = (1.f - z) * nv + z * h_s[nl][i];
        hout[(size_t)n * H + i] = hnew;
        hin[(size_t)n * H + i] = 0.f;        // pre-zero next step's agg
        hn_s[nl][i] = hnew;
        if (finalstep) {
            if (isf32) ((float*)out_any)[(size_t)n * H + i] = hnew;
            else       ((uint16_t*)out_any)[(size_t)n * H + i] = f2bf(hnew);
        }
    }
    if (emit_u && !finalstep) {
        __syncthreads();
        if (act) {
            float au = 0.f;
#pragma unroll
            for (int j = 0; j < 32; j++) au += b2_s[i * 33 + j] * hn_s[nl][j];
            u_next[(size_t)n * 32 + i] = au;
        }
    }
}

// ---- launch --------------------------------------------------------------
extern "C" void kernel_launch(void* const* d_in, const int* in_sizes, int n_in,
                              void* d_out, int out_size, void* d_ws, size_t ws_size,
                              hipStream_t stream)
{
    const void* x   = d_in[0];
    const int*  ei  = (const int*)d_in[1];
    const void* ea  = d_in[2];
    const void* wp  = d_in[3];
    const void* bp  = d_in[4];
    const void* w1  = d_in[5];
    const void* b1  = d_in[6];
    const void* w2  = d_in[7];
    const void* b2  = d_in[8];
    const void* wih = d_in[9];
    const void* whh = d_in[10];
    const void* bih = d_in[11];
    const void* bhh = d_in[12];

    int nnodes = in_sizes[0] / ND;       // 10000
    int nedges = in_sizes[1] / 2;        // 160000

    size_t hbytes = (size_t)nnodes * H * sizeof(float);          // 1.28 MB
    size_t tbytes = (size_t)nnodes * 4096 * sizeof(float);       // 163.84 MB
    if (ws_size < 256 + 2 * hbytes) return;   // absmax==max|ref| => ws too small

    size_t off = 0;
    int*   flags  = (int*)d_ws;                 off += 256;
    float* bufA   = (float*)((char*)d_ws + off); off += hbytes;
    float* bufB   = (float*)((char*)d_ws + off); off += hbytes;
    float* u_buf  = (float*)((char*)d_ws + off); off += hbytes;
    int*   deg    = (int*)((char*)d_ws + off);   off += (size_t)nnodes * 4;
    int*   cursor = (int*)((char*)d_ws + off);   off += (size_t)nnodes * 4;
    int*   perm   = (int*)((char*)d_ws + off);   off += (size_t)nedges * 4;
    off = (off + 255) & ~(size_t)255;
    float* Bperm  = (float*)((char*)d_ws + off); off += (size_t)MH * HH * 4;  // 512 KB
    off = (off + 255) & ~(size_t)255;
    float* Tall   = (float*)((char*)d_ws + off); off += tbytes;
    int hi_tier = (ws_size >= off);

    k_detect<<<1, 256, 0, stream>>>((const uint16_t*)x, ei, nedges, flags);
    k_node_proj<<<(nnodes + 7) / 8, 256, 0, stream>>>(
        x, wp, bp, b2, bufA, u_buf, nnodes, hi_tier, flags);
    hipMemsetAsync(bufB, 0, hbytes, stream);     // s=0 agg; later zeroed by k_gru

    if (hi_tier) {
        hipMemsetAsync(deg, 0, (size_t)nnodes * 4, stream);
        k_hist<<<(nedges + 255) / 256, 256, 0, stream>>>(ei, flags, deg, nedges, nnodes);
        k_scan<<<1, 256, 0, stream>>>(deg, cursor, nnodes);
        k_scatter<<<(nedges + 255) / 256, 256, 0, stream>>>(ei, flags, cursor, perm, nedges, nnodes);
        k_permw2<<<(MH * HH + 255) / 256, 256, 0, stream>>>(w2, Bperm, flags);
        // after k_scatter: cursor[n] == row end, deg[n] == row degree
    }

    float* hcur = bufA;
    float* aggb = bufB;
    for (int s = 0; s < 3; s++) {
        if (hi_tier) {
            k_T6<<<((nnodes + 127) / 128) * 8, 256, 0, stream>>>(
                Bperm, hcur, Tall, nnodes);
            k_edge6<<<(nnodes + 1) / 2, 256, 0, stream>>>(
                ea, w1, b1, Tall, u_buf, ei, perm, deg, cursor, flags,
                aggb, nedges, nnodes);
        } else {
            k_msg_valu<<<(nedges + 63) / 64, 256, 0, stream>>>(
                ea, w1, b1, w2, b2, hcur, ei, flags, aggb, nedges, nnodes);
        }
        k_gru<<<(nnodes + 7) / 8, 256, 0, stream>>>(
            aggb, hcur, wih, whh, bih, bhh, b2, u_buf, aggb, d_out,
            nnodes, s == 2, hi_tier, flags);
        float* tmp = hcur; hcur = aggb; aggb = tmp;
    }
}

// Round 16
// 810.519 us; speedup vs baseline: 1.0369x; 1.0369x over previous
//
#include <hip/hip_runtime.h>
#include <stdint.h>

#define H   32
#define ND  64
#define ED  16
#define MH  128
#define HH  1024   // H*H

__device__ __forceinline__ float bf2f(uint16_t u) {
    union { uint32_t u; float f; } v; v.u = ((uint32_t)u) << 16; return v.f;
}
__device__ __forceinline__ uint16_t f2bf(float f) {
    union { float f; uint32_t u; } v; v.f = f;
    return (uint16_t)((v.u + 0x7FFFu + ((v.u >> 16) & 1u)) >> 16);  // RNE
}
__device__ __forceinline__ float ldf(const void* p, size_t i, int isf32) {
    return isf32 ? ((const float*)p)[i] : bf2f(((const uint16_t*)p)[i]);
}

// ---- K-1: runtime dtype probes -------------------------------------------
__global__ void k_detect(const uint16_t* __restrict__ xr,
                         const int* __restrict__ ei, int nedges,
                         int* __restrict__ flags) {
    __shared__ int s_bad, s_hi;
    int t = threadIdx.x;
    if (t == 0) { s_bad = 0; s_hi = 0; }
    __syncthreads();
    int bad = 0;
    for (int i = t; i < 2048; i += 256) {
        uint16_t u = xr[i];
        int e = (u >> 7) & 0xFF;
        if (!(u == 0 || (e >= 96 && e <= 144))) bad++;
    }
    atomicAdd(&s_bad, bad);
    int mm = nedges < 4096 ? nedges : 4096;
    int hi = 0;
    for (int i = t; i < mm; i += 256) hi |= (ei[2 * i + 1] != 0);
    if (hi) atomicOr(&s_hi, 1);
    __syncthreads();
    if (t == 0) {
        flags[0] = (s_bad > 204) ? 1 : 0;   // fp32 inputs
        flags[1] = (s_hi == 0) ? 1 : 0;     // int64 edge_index
    }
}

__device__ __forceinline__ int load_idx(const int* __restrict__ ei, int is64,
                                        long long pos, int nnodes) {
    int v = is64 ? (int)(((const long long*)ei)[pos]) : ei[pos];
    v = v < 0 ? 0 : v;
    return v >= nnodes ? nnodes - 1 : v;
}

// ---- CSR-by-src build ----------------------------------------------------
__global__ void k_hist(const int* __restrict__ ei, const int* __restrict__ flags,
                       int* __restrict__ deg, int nedges, int nnodes) {
    int e = blockIdx.x * 256 + threadIdx.x;
    if (e >= nedges) return;
    int s = load_idx(ei, flags[1], e, nnodes);
    atomicAdd(&deg[s], 1);
}

__global__ void k_scan(const int* __restrict__ deg, int* __restrict__ cursor,
                       int nnodes) {
    __shared__ int tot[256];
    int t = threadIdx.x;
    int C = (nnodes + 255) >> 8;
    int b = t * C, e = b + C < nnodes ? b + C : nnodes;
    int s = 0;
    for (int i = b; i < e; i++) s += deg[i];
    tot[t] = s;
    __syncthreads();
    if (t == 0) {
        int acc = 0;
        for (int i = 0; i < 256; i++) { int v = tot[i]; tot[i] = acc; acc += v; }
    }
    __syncthreads();
    int acc = tot[t];
    for (int i = b; i < e; i++) { cursor[i] = acc; acc += deg[i]; }
}

__global__ void k_scatter(const int* __restrict__ ei, const int* __restrict__ flags,
                          int* __restrict__ cursor, int* __restrict__ perm,
                          int nedges, int nnodes) {
    int e = blockIdx.x * 256 + threadIdx.x;
    if (e >= nedges) return;
    int s = load_idx(ei, flags[1], e, nnodes);
    int p = atomicAdd(&cursor[s], 1);
    perm[p] = e;
}

// ---- K1: h0 = x @ Wp + bp  (+ fused u0 when emit_u) ----------------------
__global__ __launch_bounds__(256) void k_node_proj(
    const void* __restrict__ x, const void* __restrict__ wp,
    const void* __restrict__ bp, const void* __restrict__ b2g,
    float* __restrict__ h, float* __restrict__ u0, int nnodes,
    int emit_u, const int* __restrict__ flags)
{
    __shared__ float wp_s[ND][H];
    __shared__ float x_s[8][ND + 1];
    __shared__ float hn_s[8][33];
    __shared__ float b2_s[32 * 33];
    int isf32 = flags[0];
    int t = threadIdx.x;
    for (int i = t; i < ND * H; i += 256) wp_s[i >> 5][i & 31] = ldf(wp, i, isf32);
    for (int i = t; i < 8 * ND; i += 256) {
        int row = i >> 6, col = i & 63;
        int gn = blockIdx.x * 8 + row;
        x_s[row][col] = (gn < nnodes) ? ldf(x, (size_t)gn * ND + col, isf32) : 0.f;
    }
    if (emit_u)
        for (int i = t; i < 1024; i += 256)
            b2_s[(i >> 5) * 33 + (i & 31)] = ldf(b2g, i, isf32);
    __syncthreads();
    int nl = t >> 5, c = t & 31;
    int n = blockIdx.x * 8 + nl;
    int act = (n < nnodes);
    if (act) {
        float acc = ldf(bp, c, isf32);
#pragma unroll
        for (int k = 0; k < ND; k++) acc += x_s[nl][k] * wp_s[k][c];
        h[(size_t)n * H + c] = acc;
        hn_s[nl][c] = acc;
    }
    if (emit_u) {
        __syncthreads();
        if (act) {
            float au = 0.f;
#pragma unroll
            for (int j = 0; j < 32; j++) au += b2_s[c * 33 + j] * hn_s[nl][j];
            u0[(size_t)n * 32 + c] = au;
        }
    }
}

// ---- one-time: B'[j][i*128+k] = W2[k][i*32+j]  (512 KB fp32) -------------
__global__ void k_permw2(const void* __restrict__ w2g, float* __restrict__ Bp,
                         const int* __restrict__ flags) {
    int isf32 = flags[0];
    int idx = blockIdx.x * 256 + threadIdx.x;
    if (idx >= MH * HH) return;
    int k = idx / HH, col = idx % HH;   // col = i*32 + j
    int i = col >> 5, j = col & 31;
    Bp[(size_t)j * 4096 + i * 128 + k] = ldf(w2g, idx, isf32);
}

// ---- HI: k_T6 — skinny GEMM T = h @ B', 128-node tile, 2 blocks/CU -------
// (R14 verbatim — measured below top-5 cutoff)
__global__ __launch_bounds__(256) void k_T6(
    const float* __restrict__ Bp, const float* __restrict__ h,
    float* __restrict__ Tall, int nnodes)
{
    __shared__ float h_s[128 * 33];        // 16.9 KB
    __shared__ float occ_pad[12288];       // 48 KB: occupancy governor (2 blk/CU)
    int t = threadIdx.x;
    int cbq = blockIdx.x & 7;
    int n0 = (blockIdx.x >> 3) * 128;
    int c = cbq * 512 + t * 2;

    if (nnodes < 0) occ_pad[t] = h[t];     // never true: keeps pad allocated

    for (int i = t; i < 128 * 32; i += 256) {
        int n = i >> 5, j = i & 31;
        h_s[n * 33 + j] = (n0 + n < nnodes) ? h[(size_t)(n0 + n) * H + j] : 0.f;
    }
    float2 Breg[32];
#pragma unroll
    for (int j = 0; j < 32; j++)
        Breg[j] = *((const float2*)&Bp[(size_t)j * 4096 + c]);
    __syncthreads();

    int nmax = nnodes - n0; if (nmax > 128) nmax = 128;
    int n = 0;
    for (; n + 2 <= nmax; n += 2) {
        float2 a0 = {0.f, 0.f}, a1 = {0.f, 0.f};
#pragma unroll
        for (int j = 0; j < 32; j++) {
            float h0 = h_s[n * 33 + j], h1 = h_s[(n + 1) * 33 + j];
            float2 b = Breg[j];
            a0.x += h0 * b.x; a0.y += h0 * b.y;
            a1.x += h1 * b.x; a1.y += h1 * b.y;
        }
        *((float2*)&Tall[(size_t)(n0 + n) * 4096 + c]) = a0;
        *((float2*)&Tall[(size_t)(n0 + n + 1) * 4096 + c]) = a1;
    }
    if (n < nmax) {
        float2 a0 = {0.f, 0.f};
#pragma unroll
        for (int j = 0; j < 32; j++) {
            float h0 = h_s[n * 33 + j];
            float2 b = Breg[j];
            a0.x += h0 * b.x; a0.y += h0 * b.y;
        }
        *((float2*)&Tall[(size_t)(n0 + n) * 4096 + c]) = a0;
    }
}

// ---- HI: k_edge4 — block-per-src-node (R11/R14 verbatim: 130 us, 0 confl) -
__global__ __launch_bounds__(256) void k_edge4(
    const void* __restrict__ ea, const void* __restrict__ w1,
    const void* __restrict__ b1g, const float* __restrict__ Tall,
    const float* __restrict__ u, const int* __restrict__ ei,
    const int* __restrict__ perm, const int* __restrict__ degp,
    const int* __restrict__ rendp, const int* __restrict__ flags,
    float* __restrict__ agg, int nedges, int nnodes)
{
    int n = blockIdx.x;
    int dcount = degp[n];
    if (dcount == 0) return;
    int rstart = rendp[n] - dcount;

    __shared__ float T_lds[32 * 132];
    __shared__ float hid_s[16 * 132];
    __shared__ float w1_s[ED * MH];
    __shared__ float ea_f[16 * ED];
    __shared__ float b1_s[MH];
    __shared__ float u_lds[32];
    __shared__ int   e_s[16], d_s[16];

    int t = threadIdx.x;
    int isf32 = flags[0], is64 = flags[1];

    for (int f = t; f < 1024; f += 256) {
        float4 q = *((const float4*)&Tall[(size_t)n * 4096 + f * 4]);
        int i = f >> 5, k4 = (f & 31) * 4;
        *((float4*)&T_lds[i * 132 + k4]) = q;
    }
    for (int i = t; i < ED * MH; i += 256) w1_s[i] = ldf(w1, i, isf32);
    if (t < MH) b1_s[t] = ldf(b1g, t, isf32);
    if (t < 32) u_lds[t] = u[(size_t)n * 32 + t];

    int e_rel = t & 15, i2 = t >> 4;
    int nchunks = (dcount + 15) >> 4;

    for (int ch = 0; ch < nchunks; ch++) {
        __syncthreads();
        if (t < 16) {
            int idx = ch * 16 + t;
            int e = (idx < dcount) ? perm[rstart + idx] : -1;
            e_s[t] = e;
            d_s[t] = (e >= 0) ? load_idx(ei, is64, (long long)nedges + e, nnodes) : 0;
        }
        __syncthreads();
        for (int i = t; i < 16 * ED; i += 256) {
            int e = e_s[i >> 4];
            ea_f[i] = (e >= 0) ? ldf(ea, (size_t)e * ED + (i & 15), isf32) : 0.f;
        }
        __syncthreads();
        for (int idx = t; idx < 16 * MH; idx += 256) {
            int el = idx >> 7, c = idx & 127;
            float acc = b1_s[c];
#pragma unroll
            for (int k = 0; k < ED; k++)
                acc += ea_f[el * ED + k] * w1_s[k * MH + c];
            hid_s[el * 132 + c] = fmaxf(acc, 0.f);
        }
        __syncthreads();
        if (e_s[e_rel] >= 0) {
            float a0 = u_lds[i2], a1 = u_lds[i2 + 16];
#pragma unroll
            for (int k4 = 0; k4 < 32; k4++) {
                float4 hv = *((const float4*)&hid_s[e_rel * 132 + k4 * 4]);
                float4 t0 = *((const float4*)&T_lds[i2 * 132 + k4 * 4]);
                float4 t1 = *((const float4*)&T_lds[(i2 + 16) * 132 + k4 * 4]);
                a0 += hv.x * t0.x + hv.y * t0.y + hv.z * t0.z + hv.w * t0.w;
                a1 += hv.x * t1.x + hv.y * t1.y + hv.z * t1.z + hv.w * t1.w;
            }
            int d = d_s[e_rel];
            atomicAdd(&agg[(size_t)d * H + i2], a0);
            atomicAdd(&agg[(size_t)d * H + i2 + 16], a1);
        }
    }
}

// ---- LO tier: R5's known-good direct VALU message kernel -----------------
__global__ __launch_bounds__(256) void k_msg_valu(
    const void* __restrict__ ea, const void* __restrict__ w1,
    const void* __restrict__ b1g, const void* __restrict__ w2g,
    const void* __restrict__ b2g, const float* __restrict__ h,
    const int* __restrict__ ei, const int* __restrict__ flags,
    float* __restrict__ agg, int nedges, int nnodes)
{
    __shared__ float hid_s[64 * 130];
    __shared__ float w1_s[ED * MH];
    __shared__ float b1_s[MH];
    __shared__ float ea_f[64 * ED];

    int t = threadIdx.x;
    int e0 = blockIdx.x * 64;
    int isf32 = flags[0], is64 = flags[1];

    for (int i = t; i < 64 * ED; i += 256) {
        int e = e0 + (i >> 4);
        ea_f[i] = (e < nedges) ? ldf(ea, (size_t)e * ED + (i & 15), isf32) : 0.f;
    }
    for (int i = t; i < ED * MH; i += 256) w1_s[i] = ldf(w1, i, isf32);
    for (int i = t; i < MH; i += 256) b1_s[i] = ldf(b1g, i, isf32);
    __syncthreads();

    for (int idx = t; idx < 64 * MH; idx += 256) {
        int el = idx >> 7, c = idx & 127;
        float acc = b1_s[c];
#pragma unroll
        for (int k = 0; k < ED; k++)
            acc += ea_f[el * ED + k] * w1_s[k * MH + c];
        hid_s[el * 130 + c] = fmaxf(acc, 0.f);
    }
    __syncthreads();

    int lane = t & 63, w = t >> 6;
    int b = w * 64 + lane;
    int j = b & 31;
    int q = b >> 5;

    float b2v[4];
#pragma unroll
    for (int m = 0; m < 4; m++) b2v[m] = ldf(b2g, b + 256 * m, isf32);

    for (int g = 0; g < 4; g++) {
        float acc[16][4];
#pragma unroll
        for (int e = 0; e < 16; e++)
#pragma unroll
            for (int m = 0; m < 4; m++) acc[e][m] = 0.f;

        for (int k2 = 0; k2 < 64; k2++) {
            float w2a[4], w2b[4];
#pragma unroll
            for (int m = 0; m < 4; m++) {
                w2a[m] = ldf(w2g, (size_t)(2 * k2) * HH + b + 256 * m, isf32);
                w2b[m] = ldf(w2g, (size_t)(2 * k2 + 1) * HH + b + 256 * m, isf32);
            }
#pragma unroll
            for (int e = 0; e < 16; e++) {
                float2 hv = *((const float2*)&hid_s[(g * 16 + e) * 130 + 2 * k2]);
#pragma unroll
                for (int m = 0; m < 4; m++)
                    acc[e][m] += hv.x * w2a[m] + hv.y * w2b[m];
            }
        }

#pragma unroll
        for (int e = 0; e < 16; e++) {
            int eg = e0 + g * 16 + e;
            int valid = (eg < nedges);
            int se = valid ? load_idx(ei, is64, eg, nnodes) : 0;
            float he = h[(size_t)se * H + j];
            int d = valid ? load_idx(ei, is64, (long long)nedges + eg, nnodes) : 0;
#pragma unroll
            for (int m = 0; m < 4; m++) {
                float p = (acc[e][m] + b2v[m]) * he;
                p += __shfl_xor(p, 1);
                p += __shfl_xor(p, 2);
                p += __shfl_xor(p, 4);
                p += __shfl_xor(p, 8);
                p += __shfl_xor(p, 16);
                if ((lane & 31) == 0 && valid)
                    atomicAdd(&agg[(size_t)d * H + (q + 8 * m)], p);
            }
        }
    }
}

// ---- K3: GRU cell; zeroes hin (next agg); fused u_next when emit_u -------
__global__ __launch_bounds__(256) void k_gru(
    const float* __restrict__ agg, float* hin,
    const void* __restrict__ w_ih, const void* __restrict__ w_hh,
    const void* __restrict__ b_ih, const void* __restrict__ b_hh,
    const void* __restrict__ b2g, float* __restrict__ u_next,
    float* __restrict__ hout, void* __restrict__ out_any,
    int nnodes, int finalstep, int emit_u, const int* __restrict__ flags)
{
    __shared__ float wih_s[3 * H][H + 1];
    __shared__ float whh_s[3 * H][H + 1];
    __shared__ float bih_s[3 * H], bhh_s[3 * H];
    __shared__ float a_s[8][H + 1], h_s[8][H + 1], hn_s[8][33];
    __shared__ float b2_s[32 * 33];
    int isf32 = flags[0];
    int t = threadIdx.x;
    for (int i = t; i < 3 * H * H; i += 256) {
        wih_s[i >> 5][i & 31] = ldf(w_ih, i, isf32);
        whh_s[i >> 5][i & 31] = ldf(w_hh, i, isf32);
    }
    for (int i = t; i < 3 * H; i += 256) {
        bih_s[i] = ldf(b_ih, i, isf32);
        bhh_s[i] = ldf(b_hh, i, isf32);
    }
    if (emit_u && !finalstep)
        for (int i = t; i < 1024; i += 256)
            b2_s[(i >> 5) * 33 + (i & 31)] = ldf(b2g, i, isf32);
    int nl = t >> 5, i = t & 31;
    int n = blockIdx.x * 8 + nl;
    int act = (n < nnodes);
    if (act) {
        a_s[nl][i] = agg[(size_t)n * H + i];
        h_s[nl][i] = hin[(size_t)n * H + i];
    }
    __syncthreads();

    if (act) {
        float gr = bih_s[i], gz = bih_s[H + i], gn = bih_s[2 * H + i];
        float hr = bhh_s[i], hz = bhh_s[H + i], hn = bhh_s[2 * H + i];
#pragma unroll
        for (int jj = 0; jj < H; jj++) {
            float a = a_s[nl][jj], hh = h_s[nl][jj];
            gr += a * wih_s[i][jj];      gz += a * wih_s[H + i][jj];  gn += a * wih_s[2 * H + i][jj];
            hr += hh * whh_s[i][jj];     hz += hh * whh_s[H + i][jj]; hn += hh * whh_s[2 * H + i][jj];
        }
        float r  = 1.f / (1.f + __expf(-(gr + hr)));
        float z  = 1.f / (1.f + __expf(-(gz + hz)));
        float nv = tanhf(gn + r * hn);
        float hnew = (1.f - z) * nv + z * h_s[nl][i];
        hout[(size_t)n * H + i] = hnew;
        hin[(size_t)n * H + i] = 0.f;        // pre-zero next step's agg
        hn_s[nl][i] = hnew;
        if (finalstep) {
            if (isf32) ((float*)out_any)[(size_t)n * H + i] = hnew;
            else       ((uint16_t*)out_any)[(size_t)n * H + i] = f2bf(hnew);
        }
    }
    if (emit_u && !finalstep) {
        __syncthreads();
        if (act) {
            float au = 0.f;
#pragma unroll
            for (int j = 0; j < 32; j++) au += b2_s[i * 33 + j] * hn_s[nl][j];
            u_next[(size_t)n * 32 + i] = au;
        }
    }
}

// ---- launch --------------------------------------------------------------
extern "C" void kernel_launch(void* const* d_in, const int* in_sizes, int n_in,
                              void* d_out, int out_size, void* d_ws, size_t ws_size,
                              hipStream_t stream)
{
    const void* x   = d_in[0];
    const int*  ei  = (const int*)d_in[1];
    const void* ea  = d_in[2];
    const void* wp  = d_in[3];
    const void* bp  = d_in[4];
    const void* w1  = d_in[5];
    const void* b1  = d_in[6];
    const void* w2  = d_in[7];
    const void* b2  = d_in[8];
    const void* wih = d_in[9];
    const void* whh = d_in[10];
    const void* bih = d_in[11];
    const void* bhh = d_in[12];

    int nnodes = in_sizes[0] / ND;       // 10000
    int nedges = in_sizes[1] / 2;        // 160000

    size_t hbytes = (size_t)nnodes * H * sizeof(float);          // 1.28 MB
    size_t tbytes = (size_t)nnodes * 4096 * sizeof(float);       // 163.84 MB
    if (ws_size < 256 + 2 * hbytes) return;   // absmax==max|ref| => ws too small

    size_t off = 0;
    int*   flags  = (int*)d_ws;                 off += 256;
    float* bufA   = (float*)((char*)d_ws + off); off += hbytes;
    float* bufB   = (float*)((char*)d_ws + off); off += hbytes;
    float* u_buf  = (float*)((char*)d_ws + off); off += hbytes;
    int*   deg    = (int*)((char*)d_ws + off);   off += (size_t)nnodes * 4;
    int*   cursor = (int*)((char*)d_ws + off);   off += (size_t)nnodes * 4;
    int*   perm   = (int*)((char*)d_ws + off);   off += (size_t)nedges * 4;
    off = (off + 255) & ~(size_t)255;
    float* Bperm  = (float*)((char*)d_ws + off); off += (size_t)MH * HH * 4;  // 512 KB
    off = (off + 255) & ~(size_t)255;
    float* Tall   = (float*)((char*)d_ws + off); off += tbytes;
    int hi_tier = (ws_size >= off);

    k_detect<<<1, 256, 0, stream>>>((const uint16_t*)x, ei, nedges, flags);
    k_node_proj<<<(nnodes + 7) / 8, 256, 0, stream>>>(
        x, wp, bp, b2, bufA, u_buf, nnodes, hi_tier, flags);
    hipMemsetAsync(bufB, 0, hbytes, stream);     // s=0 agg; later zeroed by k_gru

    if (hi_tier) {
        hipMemsetAsync(deg, 0, (size_t)nnodes * 4, stream);
        k_hist<<<(nedges + 255) / 256, 256, 0, stream>>>(ei, flags, deg, nedges, nnodes);
        k_scan<<<1, 256, 0, stream>>>(deg, cursor, nnodes);
        k_scatter<<<(nedges + 255) / 256, 256, 0, stream>>>(ei, flags, cursor, perm, nedges, nnodes);
        k_permw2<<<(MH * HH + 255) / 256, 256, 0, stream>>>(w2, Bperm, flags);
        // after k_scatter: cursor[n] == row end, deg[n] == row degree
    }

    float* hcur = bufA;
    float* aggb = bufB;
    for (int s = 0; s < 3; s++) {
        if (hi_tier) {
            k_T6<<<((nnodes + 127) / 128) * 8, 256, 0, stream>>>(
                Bperm, hcur, Tall, nnodes);
            k_edge4<<<nnodes, 256, 0, stream>>>(
                ea, w1, b1, Tall, u_buf, ei, perm, deg, cursor, flags,
                aggb, nedges, nnodes);
        } else {
            k_msg_valu<<<(nedges + 63) / 64, 256, 0, stream>>>(
                ea, w1, b1, w2, b2, hcur, ei, flags, aggb, nedges, nnodes);
        }
        k_gru<<<(nnodes + 7) / 8, 256, 0, stream>>>(
            aggb, hcur, wih, whh, bih, bhh, b2, u_buf, aggb, d_out,
            nnodes, s == 2, hi_tier, flags);
        float* tmp = hcur; hcur = aggb; aggb = tmp;
    }
}

// Round 17
// 756.875 us; speedup vs baseline: 1.1104x; 1.0709x over previous
//
#include <hip/hip_runtime.h>
#include <stdint.h>

#define H   32
#define ND  64
#define ED  16
#define MH  128
#define HH  1024   // H*H

__device__ __forceinline__ float bf2f(uint16_t u) {
    union { uint32_t u; float f; } v; v.u = ((uint32_t)u) << 16; return v.f;
}
__device__ __forceinline__ uint16_t f2bf(float f) {
    union { float f; uint32_t u; } v; v.f = f;
    return (uint16_t)((v.u + 0x7FFFu + ((v.u >> 16) & 1u)) >> 16);  // RNE
}
__device__ __forceinline__ float ldf(const void* p, size_t i, int isf32) {
    return isf32 ? ((const float*)p)[i] : bf2f(((const uint16_t*)p)[i]);
}

// ---- K-1: runtime dtype probes -------------------------------------------
__global__ void k_detect(const uint16_t* __restrict__ xr,
                         const int* __restrict__ ei, int nedges,
                         int* __restrict__ flags) {
    __shared__ int s_bad, s_hi;
    int t = threadIdx.x;
    if (t == 0) { s_bad = 0; s_hi = 0; }
    __syncthreads();
    int bad = 0;
    for (int i = t; i < 2048; i += 256) {
        uint16_t u = xr[i];
        int e = (u >> 7) & 0xFF;
        if (!(u == 0 || (e >= 96 && e <= 144))) bad++;
    }
    atomicAdd(&s_bad, bad);
    int mm = nedges < 4096 ? nedges : 4096;
    int hi = 0;
    for (int i = t; i < mm; i += 256) hi |= (ei[2 * i + 1] != 0);
    if (hi) atomicOr(&s_hi, 1);
    __syncthreads();
    if (t == 0) {
        flags[0] = (s_bad > 204) ? 1 : 0;   // fp32 inputs
        flags[1] = (s_hi == 0) ? 1 : 0;     // int64 edge_index
    }
}

__device__ __forceinline__ int load_idx(const int* __restrict__ ei, int is64,
                                        long long pos, int nnodes) {
    int v = is64 ? (int)(((const long long*)ei)[pos]) : ei[pos];
    v = v < 0 ? 0 : v;
    return v >= nnodes ? nnodes - 1 : v;
}

// ---- CSR-by-src build ----------------------------------------------------
__global__ void k_hist(const int* __restrict__ ei, const int* __restrict__ flags,
                       int* __restrict__ deg, int nedges, int nnodes) {
    int e = blockIdx.x * 256 + threadIdx.x;
    if (e >= nedges) return;
    int s = load_idx(ei, flags[1], e, nnodes);
    atomicAdd(&deg[s], 1);
}

__global__ void k_scan(const int* __restrict__ deg, int* __restrict__ cursor,
                       int nnodes) {
    __shared__ int tot[256];
    int t = threadIdx.x;
    int C = (nnodes + 255) >> 8;
    int b = t * C, e = b + C < nnodes ? b + C : nnodes;
    int s = 0;
    for (int i = b; i < e; i++) s += deg[i];
    tot[t] = s;
    __syncthreads();
    if (t == 0) {
        int acc = 0;
        for (int i = 0; i < 256; i++) { int v = tot[i]; tot[i] = acc; acc += v; }
    }
    __syncthreads();
    int acc = tot[t];
    for (int i = b; i < e; i++) { cursor[i] = acc; acc += deg[i]; }
}

__global__ void k_scatter(const int* __restrict__ ei, const int* __restrict__ flags,
                          int* __restrict__ cursor, int* __restrict__ perm,
                          int nedges, int nnodes) {
    int e = blockIdx.x * 256 + threadIdx.x;
    if (e >= nedges) return;
    int s = load_idx(ei, flags[1], e, nnodes);
    int p = atomicAdd(&cursor[s], 1);
    perm[p] = e;
}

// ---- K1: h0 = x @ Wp + bp  (+ fused u0 when emit_u) ----------------------
__global__ __launch_bounds__(256) void k_node_proj(
    const void* __restrict__ x, const void* __restrict__ wp,
    const void* __restrict__ bp, const void* __restrict__ b2g,
    float* __restrict__ h, float* __restrict__ u0, int nnodes,
    int emit_u, const int* __restrict__ flags)
{
    __shared__ float wp_s[ND][H];
    __shared__ float x_s[8][ND + 1];
    __shared__ float hn_s[8][33];
    __shared__ float b2_s[32 * 33];
    int isf32 = flags[0];
    int t = threadIdx.x;
    for (int i = t; i < ND * H; i += 256) wp_s[i >> 5][i & 31] = ldf(wp, i, isf32);
    for (int i = t; i < 8 * ND; i += 256) {
        int row = i >> 6, col = i & 63;
        int gn = blockIdx.x * 8 + row;
        x_s[row][col] = (gn < nnodes) ? ldf(x, (size_t)gn * ND + col, isf32) : 0.f;
    }
    if (emit_u)
        for (int i = t; i < 1024; i += 256)
            b2_s[(i >> 5) * 33 + (i & 31)] = ldf(b2g, i, isf32);
    __syncthreads();
    int nl = t >> 5, c = t & 31;
    int n = blockIdx.x * 8 + nl;
    int act = (n < nnodes);
    if (act) {
        float acc = ldf(bp, c, isf32);
#pragma unroll
        for (int k = 0; k < ND; k++) acc += x_s[nl][k] * wp_s[k][c];
        h[(size_t)n * H + c] = acc;
        hn_s[nl][c] = acc;
    }
    if (emit_u) {
        __syncthreads();
        if (act) {
            float au = 0.f;
#pragma unroll
            for (int j = 0; j < 32; j++) au += b2_s[c * 33 + j] * hn_s[nl][j];
            u0[(size_t)n * 32 + c] = au;
        }
    }
}

// ---- one-time: B'[j][i*128+k] = W2[k][i*32+j]  (512 KB fp32) -------------
__global__ void k_permw2(const void* __restrict__ w2g, float* __restrict__ Bp,
                         const int* __restrict__ flags) {
    int isf32 = flags[0];
    int idx = blockIdx.x * 256 + threadIdx.x;
    if (idx >= MH * HH) return;
    int k = idx / HH, col = idx % HH;   // col = i*32 + j
    int i = col >> 5, j = col & 31;
    Bp[(size_t)j * 4096 + i * 128 + k] = ldf(w2g, idx, isf32);
}

// ---- one-time: w1 as fp32 (for k_edge8's register loads) + b1 fp32 -------
__global__ void k_prepw1(const void* __restrict__ w1g, const void* __restrict__ b1g,
                         float* __restrict__ w1f, float* __restrict__ b1f,
                         const int* __restrict__ flags) {
    int isf32 = flags[0];
    int idx = blockIdx.x * 256 + threadIdx.x;
    if (idx < ED * MH) w1f[idx] = ldf(w1g, idx, isf32);
    if (idx < MH) b1f[idx] = ldf(b1g, idx, isf32);
}

// ---- HI: k_T6 — skinny GEMM T = h @ B', 128-node tile, 2 blocks/CU -------
// (R14 verbatim — measured below top-5 cutoff)
__global__ __launch_bounds__(256) void k_T6(
    const float* __restrict__ Bp, const float* __restrict__ h,
    float* __restrict__ Tall, int nnodes)
{
    __shared__ float h_s[128 * 33];        // 16.9 KB
    __shared__ float occ_pad[12288];       // 48 KB: occupancy governor (2 blk/CU)
    int t = threadIdx.x;
    int cbq = blockIdx.x & 7;
    int n0 = (blockIdx.x >> 3) * 128;
    int c = cbq * 512 + t * 2;

    if (nnodes < 0) occ_pad[t] = h[t];     // never true: keeps pad allocated

    for (int i = t; i < 128 * 32; i += 256) {
        int n = i >> 5, j = i & 31;
        h_s[n * 33 + j] = (n0 + n < nnodes) ? h[(size_t)(n0 + n) * H + j] : 0.f;
    }
    float2 Breg[32];
#pragma unroll
    for (int j = 0; j < 32; j++)
        Breg[j] = *((const float2*)&Bp[(size_t)j * 4096 + c]);
    __syncthreads();

    int nmax = nnodes - n0; if (nmax > 128) nmax = 128;
    int n = 0;
    for (; n + 2 <= nmax; n += 2) {
        float2 a0 = {0.f, 0.f}, a1 = {0.f, 0.f};
#pragma unroll
        for (int j = 0; j < 32; j++) {
            float h0 = h_s[n * 33 + j], h1 = h_s[(n + 1) * 33 + j];
            float2 b = Breg[j];
            a0.x += h0 * b.x; a0.y += h0 * b.y;
            a1.x += h1 * b.x; a1.y += h1 * b.y;
        }
        *((float2*)&Tall[(size_t)(n0 + n) * 4096 + c]) = a0;
        *((float2*)&Tall[(size_t)(n0 + n + 1) * 4096 + c]) = a1;
    }
    if (n < nmax) {
        float2 a0 = {0.f, 0.f};
#pragma unroll
        for (int j = 0; j < 32; j++) {
            float h0 = h_s[n * 33 + j];
            float2 b = Breg[j];
            a0.x += h0 * b.x; a0.y += h0 * b.y;
        }
        *((float2*)&Tall[(size_t)(n0 + n) * 4096 + c]) = a0;
    }
}

// ---- HI: k_edge8 — edge4 with w1/b1 in REGISTERS -------------------------
// Lane permanently holds w1 cols (2*lane, 2*lane+1) for all 16 k (float2 x16,
// 32 VGPR) + b1 pair. Stage-1: wave w computes edges {4w..4w+3}; ea reads are
// wave-broadcast (free); hid written as aligned float2 (same k-order => hid
// bit-identical to edge4). w1/b1 LDS staging eliminated; LDS 35.3->26.6 KB.
__global__ __launch_bounds__(256) void k_edge8(
    const void* __restrict__ ea, const float* __restrict__ w1f,
    const float* __restrict__ b1f, const float* __restrict__ Tall,
    const float* __restrict__ u, const int* __restrict__ ei,
    const int* __restrict__ perm, const int* __restrict__ degp,
    const int* __restrict__ rendp, const int* __restrict__ flags,
    float* __restrict__ agg, int nedges, int nnodes)
{
    int n = blockIdx.x;
    int dcount = degp[n];
    if (dcount == 0) return;
    int rstart = rendp[n] - dcount;

    __shared__ float T_lds[32 * 132];    // 16896 B
    __shared__ float hid_s[16 * 132];    //  8448 B
    __shared__ float ea_f[16 * ED];      //  1024 B
    __shared__ float u_lds[32];
    __shared__ int   e_s[16], d_s[16];

    int t = threadIdx.x;
    int lane = t & 63, wv = t >> 6;
    int isf32 = flags[0], is64 = flags[1];

    // w1 register slice: cols c0 = 2*lane, c0+1 for k = 0..15  (coalesced f2)
    int c0 = 2 * lane;
    float2 w1r[ED];
#pragma unroll
    for (int k = 0; k < ED; k++)
        w1r[k] = *((const float2*)&w1f[k * MH + c0]);
    float2 b1r = *((const float2*)&b1f[c0]);

    for (int f = t; f < 1024; f += 256) {
        float4 q = *((const float4*)&Tall[(size_t)n * 4096 + f * 4]);
        int i = f >> 5, k4 = (f & 31) * 4;
        *((float4*)&T_lds[i * 132 + k4]) = q;
    }
    if (t < 32) u_lds[t] = u[(size_t)n * 32 + t];

    int e_rel = t & 15, i2 = t >> 4;
    int nchunks = (dcount + 15) >> 4;

    for (int ch = 0; ch < nchunks; ch++) {
        __syncthreads();   // T/u staged (ch 0); prev chunk consumed (ch>0)
        if (t < 16) {
            int idx = ch * 16 + t;
            int e = (idx < dcount) ? perm[rstart + idx] : -1;
            e_s[t] = e;
            d_s[t] = (e >= 0) ? load_idx(ei, is64, (long long)nedges + e, nnodes) : 0;
        }
        __syncthreads();
        for (int i = t; i < 16 * ED; i += 256) {
            int e = e_s[i >> 4];
            ea_f[i] = (e >= 0) ? ldf(ea, (size_t)e * ED + (i & 15), isf32) : 0.f;
        }
        __syncthreads();
        // stage 1: wave wv -> edges 4wv..4wv+3; lane -> cols c0, c0+1
#pragma unroll
        for (int er = 0; er < 4; er++) {
            int el = wv * 4 + er;
            float a0 = b1r.x, a1 = b1r.y;
#pragma unroll
            for (int k = 0; k < ED; k++) {
                float ev = ea_f[el * ED + k];   // wave-broadcast read
                a0 += ev * w1r[k].x;
                a1 += ev * w1r[k].y;
            }
            float2 o = { fmaxf(a0, 0.f), fmaxf(a1, 0.f) };
            *((float2*)&hid_s[el * 132 + c0]) = o;
        }
        __syncthreads();
        // contraction (edge4 verbatim): thread (e_rel, i2)
        if (e_s[e_rel] >= 0) {
            float a0 = u_lds[i2], a1 = u_lds[i2 + 16];
#pragma unroll
            for (int k4 = 0; k4 < 32; k4++) {
                float4 hv = *((const float4*)&hid_s[e_rel * 132 + k4 * 4]);
                float4 t0 = *((const float4*)&T_lds[i2 * 132 + k4 * 4]);
                float4 t1 = *((const float4*)&T_lds[(i2 + 16) * 132 + k4 * 4]);
                a0 += hv.x * t0.x + hv.y * t0.y + hv.z * t0.z + hv.w * t0.w;
                a1 += hv.x * t1.x + hv.y * t1.y + hv.z * t1.z + hv.w * t1.w;
            }
            int d = d_s[e_rel];
            atomicAdd(&agg[(size_t)d * H + i2], a0);
            atomicAdd(&agg[(size_t)d * H + i2 + 16], a1);
        }
    }
}

// ---- LO tier: R5's known-good direct VALU message kernel -----------------
__global__ __launch_bounds__(256) void k_msg_valu(
    const void* __restrict__ ea, const void* __restrict__ w1,
    const void* __restrict__ b1g, const void* __restrict__ w2g,
    const void* __restrict__ b2g, const float* __restrict__ h,
    const int* __restrict__ ei, const int* __restrict__ flags,
    float* __restrict__ agg, int nedges, int nnodes)
{
    __shared__ float hid_s[64 * 130];
    __shared__ float w1_s[ED * MH];
    __shared__ float b1_s[MH];
    __shared__ float ea_f[64 * ED];

    int t = threadIdx.x;
    int e0 = blockIdx.x * 64;
    int isf32 = flags[0], is64 = flags[1];

    for (int i = t; i < 64 * ED; i += 256) {
        int e = e0 + (i >> 4);
        ea_f[i] = (e < nedges) ? ldf(ea, (size_t)e * ED + (i & 15), isf32) : 0.f;
    }
    for (int i = t; i < ED * MH; i += 256) w1_s[i] = ldf(w1, i, isf32);
    for (int i = t; i < MH; i += 256) b1_s[i] = ldf(b1g, i, isf32);
    __syncthreads();

    for (int idx = t; idx < 64 * MH; idx += 256) {
        int el = idx >> 7, c = idx & 127;
        float acc = b1_s[c];
#pragma unroll
        for (int k = 0; k < ED; k++)
            acc += ea_f[el * ED + k] * w1_s[k * MH + c];
        hid_s[el * 130 + c] = fmaxf(acc, 0.f);
    }
    __syncthreads();

    int lane = t & 63, w = t >> 6;
    int b = w * 64 + lane;
    int j = b & 31;
    int q = b >> 5;

    float b2v[4];
#pragma unroll
    for (int m = 0; m < 4; m++) b2v[m] = ldf(b2g, b + 256 * m, isf32);

    for (int g = 0; g < 4; g++) {
        float acc[16][4];
#pragma unroll
        for (int e = 0; e < 16; e++)
#pragma unroll
            for (int m = 0; m < 4; m++) acc[e][m] = 0.f;

        for (int k2 = 0; k2 < 64; k2++) {
            float w2a[4], w2b[4];
#pragma unroll
            for (int m = 0; m < 4; m++) {
                w2a[m] = ldf(w2g, (size_t)(2 * k2) * HH + b + 256 * m, isf32);
                w2b[m] = ldf(w2g, (size_t)(2 * k2 + 1) * HH + b + 256 * m, isf32);
            }
#pragma unroll
            for (int e = 0; e < 16; e++) {
                float2 hv = *((const float2*)&hid_s[(g * 16 + e) * 130 + 2 * k2]);
#pragma unroll
                for (int m = 0; m < 4; m++)
                    acc[e][m] += hv.x * w2a[m] + hv.y * w2b[m];
            }
        }

#pragma unroll
        for (int e = 0; e < 16; e++) {
            int eg = e0 + g * 16 + e;
            int valid = (eg < nedges);
            int se = valid ? load_idx(ei, is64, eg, nnodes) : 0;
            float he = h[(size_t)se * H + j];
            int d = valid ? load_idx(ei, is64, (long long)nedges + eg, nnodes) : 0;
#pragma unroll
            for (int m = 0; m < 4; m++) {
                float p = (acc[e][m] + b2v[m]) * he;
                p += __shfl_xor(p, 1);
                p += __shfl_xor(p, 2);
                p += __shfl_xor(p, 4);
                p += __shfl_xor(p, 8);
                p += __shfl_xor(p, 16);
                if ((lane & 31) == 0 && valid)
                    atomicAdd(&agg[(size_t)d * H + (q + 8 * m)], p);
            }
        }
    }
}

// ---- K3: GRU cell; zeroes hin (next agg); fused u_next when emit_u -------
__global__ __launch_bounds__(256) void k_gru(
    const float* __restrict__ agg, float* hin,
    const void* __restrict__ w_ih, const void* __restrict__ w_hh,
    const void* __restrict__ b_ih, const void* __restrict__ b_hh,
    const void* __restrict__ b2g, float* __restrict__ u_next,
    float* __restrict__ hout, void* __restrict__ out_any,
    int nnodes, int finalstep, int emit_u, const int* __restrict__ flags)
{
    __shared__ float wih_s[3 * H][H + 1];
    __shared__ float whh_s[3 * H][H + 1];
    __shared__ float bih_s[3 * H], bhh_s[3 * H];
    __shared__ float a_s[8][H + 1], h_s[8][H + 1], hn_s[8][33];
    __shared__ float b2_s[32 * 33];
    int isf32 = flags[0];
    int t = threadIdx.x;
    for (int i = t; i < 3 * H * H; i += 256) {
        wih_s[i >> 5][i & 31] = ldf(w_ih, i, isf32);
        whh_s[i >> 5][i & 31] = ldf(w_hh, i, isf32);
    }
    for (int i = t; i < 3 * H; i += 256) {
        bih_s[i] = ldf(b_ih, i, isf32);
        bhh_s[i] = ldf(b_hh, i, isf32);
    }
    if (emit_u && !finalstep)
        for (int i = t; i < 1024; i += 256)
            b2_s[(i >> 5) * 33 + (i & 31)] = ldf(b2g, i, isf32);
    int nl = t >> 5, i = t & 31;
    int n = blockIdx.x * 8 + nl;
    int act = (n < nnodes);
    if (act) {
        a_s[nl][i] = agg[(size_t)n * H + i];
        h_s[nl][i] = hin[(size_t)n * H + i];
    }
    __syncthreads();

    if (act) {
        float gr = bih_s[i], gz = bih_s[H + i], gn = bih_s[2 * H + i];
        float hr = bhh_s[i], hz = bhh_s[H + i], hn = bhh_s[2 * H + i];
#pragma unroll
        for (int jj = 0; jj < H; jj++) {
            float a = a_s[nl][jj], hh = h_s[nl][jj];
            gr += a * wih_s[i][jj];      gz += a * wih_s[H + i][jj];  gn += a * wih_s[2 * H + i][jj];
            hr += hh * whh_s[i][jj];     hz += hh * whh_s[H + i][jj]; hn += hh * whh_s[2 * H + i][jj];
        }
        float r  = 1.f / (1.f + __expf(-(gr + hr)));
        float z  = 1.f / (1.f + __expf(-(gz + hz)));
        float nv = tanhf(gn + r * hn);
        float hnew = (1.f - z) * nv + z * h_s[nl][i];
        hout[(size_t)n * H + i] = hnew;
        hin[(size_t)n * H + i] = 0.f;        // pre-zero next step's agg
        hn_s[nl][i] = hnew;
        if (finalstep) {
            if (isf32) ((float*)out_any)[(size_t)n * H + i] = hnew;
            else       ((uint16_t*)out_any)[(size_t)n * H + i] = f2bf(hnew);
        }
    }
    if (emit_u && !finalstep) {
        __syncthreads();
        if (act) {
            float au = 0.f;
#pragma unroll
            for (int j = 0; j < 32; j++) au += b2_s[i * 33 + j] * hn_s[nl][j];
            u_next[(size_t)n * 32 + i] = au;
        }
    }
}

// ---- launch --------------------------------------------------------------
extern "C" void kernel_launch(void* const* d_in, const int* in_sizes, int n_in,
                              void* d_out, int out_size, void* d_ws, size_t ws_size,
                              hipStream_t stream)
{
    const void* x   = d_in[0];
    const int*  ei  = (const int*)d_in[1];
    const void* ea  = d_in[2];
    const void* wp  = d_in[3];
    const void* bp  = d_in[4];
    const void* w1  = d_in[5];
    const void* b1  = d_in[6];
    const void* w2  = d_in[7];
    const void* b2  = d_in[8];
    const void* wih = d_in[9];
    const void* whh = d_in[10];
    const void* bih = d_in[11];
    const void* bhh = d_in[12];

    int nnodes = in_sizes[0] / ND;       // 10000
    int nedges = in_sizes[1] / 2;        // 160000

    size_t hbytes = (size_t)nnodes * H * sizeof(float);          // 1.28 MB
    size_t tbytes = (size_t)nnodes * 4096 * sizeof(float);       // 163.84 MB
    if (ws_size < 256 + 2 * hbytes) return;   // absmax==max|ref| => ws too small

    size_t off = 0;
    int*   flags  = (int*)d_ws;                 off += 256;
    float* bufA   = (float*)((char*)d_ws + off); off += hbytes;
    float* bufB   = (float*)((char*)d_ws + off); off += hbytes;
    float* u_buf  = (float*)((char*)d_ws + off); off += hbytes;
    int*   deg    = (int*)((char*)d_ws + off);   off += (size_t)nnodes * 4;
    int*   cursor = (int*)((char*)d_ws + off);   off += (size_t)nnodes * 4;
    int*   perm   = (int*)((char*)d_ws + off);   off += (size_t)nedges * 4;
    off = (off + 255) & ~(size_t)255;
    float* Bperm  = (float*)((char*)d_ws + off); off += (size_t)MH * HH * 4;  // 512 KB
    float* w1f    = (float*)((char*)d_ws + off); off += (size_t)ED * MH * 4;  // 8 KB
    float* b1f    = (float*)((char*)d_ws + off); off += (size_t)MH * 4;       // 512 B
    off = (off + 255) & ~(size_t)255;
    float* Tall   = (float*)((char*)d_ws + off); off += tbytes;
    int hi_tier = (ws_size >= off);

    k_detect<<<1, 256, 0, stream>>>((const uint16_t*)x, ei, nedges, flags);
    k_node_proj<<<(nnodes + 7) / 8, 256, 0, stream>>>(
        x, wp, bp, b2, bufA, u_buf, nnodes, hi_tier, flags);
    hipMemsetAsync(bufB, 0, hbytes, stream);     // s=0 agg; later zeroed by k_gru

    if (hi_tier) {
        hipMemsetAsync(deg, 0, (size_t)nnodes * 4, stream);
        k_hist<<<(nedges + 255) / 256, 256, 0, stream>>>(ei, flags, deg, nedges, nnodes);
        k_scan<<<1, 256, 0, stream>>>(deg, cursor, nnodes);
        k_scatter<<<(nedges + 255) / 256, 256, 0, stream>>>(ei, flags, cursor, perm, nedges, nnodes);
        k_permw2<<<(MH * HH + 255) / 256, 256, 0, stream>>>(w2, Bperm, flags);
        k_prepw1<<<(ED * MH + 255) / 256, 256, 0, stream>>>(w1, b1, w1f, b1f, flags);
        // after k_scatter: cursor[n] == row end, deg[n] == row degree
    }

    float* hcur = bufA;
    float* aggb = bufB;
    for (int s = 0; s < 3; s++) {
        if (hi_tier) {
            k_T6<<<((nnodes + 127) / 128) * 8, 256, 0, stream>>>(
                Bperm, hcur, Tall, nnodes);
            k_edge8<<<nnodes, 256, 0, stream>>>(
                ea, w1f, b1f, Tall, u_buf, ei, perm, deg, cursor, flags,
                aggb, nedges, nnodes);
        } else {
            k_msg_valu<<<(nedges + 63) / 64, 256, 0, stream>>>(
                ea, w1, b1, w2, b2, hcur, ei, flags, aggb, nedges, nnodes);
        }
        k_gru<<<(nnodes + 7) / 8, 256, 0, stream>>>(
            aggb, hcur, wih, whh, bih, bhh, b2, u_buf, aggb, d_out,
            nnodes, s == 2, hi_tier, flags);
        float* tmp = hcur; hcur = aggb; aggb = tmp;
    }
}

// Round 18
// 728.294 us; speedup vs baseline: 1.1540x; 1.0392x over previous
//
#include <hip/hip_runtime.h>
#include <stdint.h>

#define H   32
#define ND  64
#define ED  16
#define MH  128
#define HH  1024   // H*H

__device__ __forceinline__ float bf2f(uint16_t u) {
    union { uint32_t u; float f; } v; v.u = ((uint32_t)u) << 16; return v.f;
}
__device__ __forceinline__ uint16_t f2bf(float f) {
    union { float f; uint32_t u; } v; v.f = f;
    return (uint16_t)((v.u + 0x7FFFu + ((v.u >> 16) & 1u)) >> 16);  // RNE
}
__device__ __forceinline__ float ldf(const void* p, size_t i, int isf32) {
    return isf32 ? ((const float*)p)[i] : bf2f(((const uint16_t*)p)[i]);
}

// ---- K-1: runtime dtype probes -------------------------------------------
__global__ void k_detect(const uint16_t* __restrict__ xr,
                         const int* __restrict__ ei, int nedges,
                         int* __restrict__ flags) {
    __shared__ int s_bad, s_hi;
    int t = threadIdx.x;
    if (t == 0) { s_bad = 0; s_hi = 0; }
    __syncthreads();
    int bad = 0;
    for (int i = t; i < 2048; i += 256) {
        uint16_t u = xr[i];
        int e = (u >> 7) & 0xFF;
        if (!(u == 0 || (e >= 96 && e <= 144))) bad++;
    }
    atomicAdd(&s_bad, bad);
    int mm = nedges < 4096 ? nedges : 4096;
    int hi = 0;
    for (int i = t; i < mm; i += 256) hi |= (ei[2 * i + 1] != 0);
    if (hi) atomicOr(&s_hi, 1);
    __syncthreads();
    if (t == 0) {
        flags[0] = (s_bad > 204) ? 1 : 0;   // fp32 inputs
        flags[1] = (s_hi == 0) ? 1 : 0;     // int64 edge_index
    }
}

__device__ __forceinline__ int load_idx(const int* __restrict__ ei, int is64,
                                        long long pos, int nnodes) {
    int v = is64 ? (int)(((const long long*)ei)[pos]) : ei[pos];
    v = v < 0 ? 0 : v;
    return v >= nnodes ? nnodes - 1 : v;
}

// ---- CSR-by-src build ----------------------------------------------------
__global__ void k_hist(const int* __restrict__ ei, const int* __restrict__ flags,
                       int* __restrict__ deg, int nedges, int nnodes) {
    int e = blockIdx.x * 256 + threadIdx.x;
    if (e >= nedges) return;
    int s = load_idx(ei, flags[1], e, nnodes);
    atomicAdd(&deg[s], 1);
}

__global__ void k_scan(const int* __restrict__ deg, int* __restrict__ cursor,
                       int nnodes) {
    __shared__ int tot[256];
    int t = threadIdx.x;
    int C = (nnodes + 255) >> 8;
    int b = t * C, e = b + C < nnodes ? b + C : nnodes;
    int s = 0;
    for (int i = b; i < e; i++) s += deg[i];
    tot[t] = s;
    __syncthreads();
    if (t == 0) {
        int acc = 0;
        for (int i = 0; i < 256; i++) { int v = tot[i]; tot[i] = acc; acc += v; }
    }
    __syncthreads();
    int acc = tot[t];
    for (int i = b; i < e; i++) { cursor[i] = acc; acc += deg[i]; }
}

__global__ void k_scatter(const int* __restrict__ ei, const int* __restrict__ flags,
                          int* __restrict__ cursor, int* __restrict__ perm,
                          int nedges, int nnodes) {
    int e = blockIdx.x * 256 + threadIdx.x;
    if (e >= nedges) return;
    int s = load_idx(ei, flags[1], e, nnodes);
    int p = atomicAdd(&cursor[s], 1);
    perm[p] = e;
}

// ---- K1: h0 = x @ Wp + bp  (+ fused u0 when emit_u) ----------------------
__global__ __launch_bounds__(256) void k_node_proj(
    const void* __restrict__ x, const void* __restrict__ wp,
    const void* __restrict__ bp, const void* __restrict__ b2g,
    float* __restrict__ h, float* __restrict__ u0, int nnodes,
    int emit_u, const int* __restrict__ flags)
{
    __shared__ float wp_s[ND][H];
    __shared__ float x_s[8][ND + 1];
    __shared__ float hn_s[8][33];
    __shared__ float b2_s[32 * 33];
    int isf32 = flags[0];
    int t = threadIdx.x;
    for (int i = t; i < ND * H; i += 256) wp_s[i >> 5][i & 31] = ldf(wp, i, isf32);
    for (int i = t; i < 8 * ND; i += 256) {
        int row = i >> 6, col = i & 63;
        int gn = blockIdx.x * 8 + row;
        x_s[row][col] = (gn < nnodes) ? ldf(x, (size_t)gn * ND + col, isf32) : 0.f;
    }
    if (emit_u)
        for (int i = t; i < 1024; i += 256)
            b2_s[(i >> 5) * 33 + (i & 31)] = ldf(b2g, i, isf32);
    __syncthreads();
    int nl = t >> 5, c = t & 31;
    int n = blockIdx.x * 8 + nl;
    int act = (n < nnodes);
    if (act) {
        float acc = ldf(bp, c, isf32);
#pragma unroll
        for (int k = 0; k < ND; k++) acc += x_s[nl][k] * wp_s[k][c];
        h[(size_t)n * H + c] = acc;
        hn_s[nl][c] = acc;
    }
    if (emit_u) {
        __syncthreads();
        if (act) {
            float au = 0.f;
#pragma unroll
            for (int j = 0; j < 32; j++) au += b2_s[c * 33 + j] * hn_s[nl][j];
            u0[(size_t)n * 32 + c] = au;
        }
    }
}

// ---- one-time: B'[j][i*128+k] = W2[k][i*32+j]  (512 KB fp32) -------------
__global__ void k_permw2(const void* __restrict__ w2g, float* __restrict__ Bp,
                         const int* __restrict__ flags) {
    int isf32 = flags[0];
    int idx = blockIdx.x * 256 + threadIdx.x;
    if (idx >= MH * HH) return;
    int k = idx / HH, col = idx % HH;   // col = i*32 + j
    int i = col >> 5, j = col & 31;
    Bp[(size_t)j * 4096 + i * 128 + k] = ldf(w2g, idx, isf32);
}

// ---- one-time: w1 as fp32 (for k_edge9's register loads) + b1 fp32 -------
__global__ void k_prepw1(const void* __restrict__ w1g, const void* __restrict__ b1g,
                         float* __restrict__ w1f, float* __restrict__ b1f,
                         const int* __restrict__ flags) {
    int isf32 = flags[0];
    int idx = blockIdx.x * 256 + threadIdx.x;
    if (idx < ED * MH) w1f[idx] = ldf(w1g, idx, isf32);
    if (idx < MH) b1f[idx] = ldf(b1g, idx, isf32);
}

// ---- HI: k_T6 — skinny GEMM T = h @ B', 128-node tile, 2 blocks/CU -------
// (R14 verbatim — measured below top-5 cutoff)
__global__ __launch_bounds__(256) void k_T6(
    const float* __restrict__ Bp, const float* __restrict__ h,
    float* __restrict__ Tall, int nnodes)
{
    __shared__ float h_s[128 * 33];        // 16.9 KB
    __shared__ float occ_pad[12288];       // 48 KB: occupancy governor (2 blk/CU)
    int t = threadIdx.x;
    int cbq = blockIdx.x & 7;
    int n0 = (blockIdx.x >> 3) * 128;
    int c = cbq * 512 + t * 2;

    if (nnodes < 0) occ_pad[t] = h[t];     // never true: keeps pad allocated

    for (int i = t; i < 128 * 32; i += 256) {
        int n = i >> 5, j = i & 31;
        h_s[n * 33 + j] = (n0 + n < nnodes) ? h[(size_t)(n0 + n) * H + j] : 0.f;
    }
    float2 Breg[32];
#pragma unroll
    for (int j = 0; j < 32; j++)
        Breg[j] = *((const float2*)&Bp[(size_t)j * 4096 + c]);
    __syncthreads();

    int nmax = nnodes - n0; if (nmax > 128) nmax = 128;
    int n = 0;
    for (; n + 2 <= nmax; n += 2) {
        float2 a0 = {0.f, 0.f}, a1 = {0.f, 0.f};
#pragma unroll
        for (int j = 0; j < 32; j++) {
            float h0 = h_s[n * 33 + j], h1 = h_s[(n + 1) * 33 + j];
            float2 b = Breg[j];
            a0.x += h0 * b.x; a0.y += h0 * b.y;
            a1.x += h1 * b.x; a1.y += h1 * b.y;
        }
        *((float2*)&Tall[(size_t)(n0 + n) * 4096 + c]) = a0;
        *((float2*)&Tall[(size_t)(n0 + n + 1) * 4096 + c]) = a1;
    }
    if (n < nmax) {
        float2 a0 = {0.f, 0.f};
#pragma unroll
        for (int j = 0; j < 32; j++) {
            float h0 = h_s[n * 33 + j];
            float2 b = Breg[j];
            a0.x += h0 * b.x; a0.y += h0 * b.y;
        }
        *((float2*)&Tall[(size_t)(n0 + n) * 4096 + c]) = a0;
    }
}

// ---- HI: k_edge9 — edge8 + T register-prefetch + barrier removal ---------
// T row loaded into registers at block top (vmcnt in flight across ea-stage
// and stage-1), committed to LDS just before the contraction barrier. e/d
// staged arrays removed (per-thread direct perm/ei loads, L2 broadcast).
// Math bit-identical to edge8.
__global__ __launch_bounds__(256) void k_edge9(
    const void* __restrict__ ea, const float* __restrict__ w1f,
    const float* __restrict__ b1f, const float* __restrict__ Tall,
    const float* __restrict__ u, const int* __restrict__ ei,
    const int* __restrict__ perm, const int* __restrict__ degp,
    const int* __restrict__ rendp, const int* __restrict__ flags,
    float* __restrict__ agg, int nedges, int nnodes)
{
    int n = blockIdx.x;
    int dcount = degp[n];
    if (dcount == 0) return;
    int rstart = rendp[n] - dcount;

    __shared__ float T_lds[32 * 132];    // 16896 B (proven conflict-free layout)
    __shared__ float hid_s[16 * 132];    //  8448 B
    __shared__ float ea_f[16 * ED];      //  1024 B
    __shared__ float u_lds[32];

    int t = threadIdx.x;
    int lane = t & 63, wv = t >> 6;
    int isf32 = flags[0], is64 = flags[1];

    // T prefetch: issue first, consume last (overlaps ea-stage + stage-1)
    const float4* Trow4 = (const float4*)(Tall + (size_t)n * 4096);
    float4 tq0 = Trow4[t];
    float4 tq1 = Trow4[t + 256];
    float4 tq2 = Trow4[t + 512];
    float4 tq3 = Trow4[t + 768];

    // w1 register slice: cols c0 = 2*lane, c0+1 for k = 0..15
    int c0 = 2 * lane;
    float2 w1r[ED];
#pragma unroll
    for (int k = 0; k < ED; k++)
        w1r[k] = *((const float2*)&w1f[k * MH + c0]);
    float2 b1r = *((const float2*)&b1f[c0]);

    if (t < 32) u_lds[t] = u[(size_t)n * 32 + t];

    int e_rel = t & 15, i2 = t >> 4;
    int nchunks = (dcount + 15) >> 4;

    for (int ch = 0; ch < nchunks; ch++) {
        if (ch > 0) __syncthreads();   // protect ea_f/hid_s reuse
        {   // ea stage: one item/thread (slot = t>>4, feat = t&15)
            int slot = t >> 4, kk = t & 15;
            int idx = ch * 16 + slot;
            int e = (idx < dcount) ? perm[rstart + idx] : -1;   // L2 broadcast
            ea_f[slot * ED + kk] = (e >= 0) ? ldf(ea, (size_t)e * ED + kk, isf32)
                                            : 0.f;
        }
        __syncthreads();
        // stage 1: wave wv -> edges 4wv..4wv+3; lane -> cols c0, c0+1
#pragma unroll
        for (int er = 0; er < 4; er++) {
            int el = wv * 4 + er;
            float a0 = b1r.x, a1 = b1r.y;
#pragma unroll
            for (int k = 0; k < ED; k++) {
                float ev = ea_f[el * ED + k];   // wave-broadcast read
                a0 += ev * w1r[k].x;
                a1 += ev * w1r[k].y;
            }
            float2 o = { fmaxf(a0, 0.f), fmaxf(a1, 0.f) };
            *((float2*)&hid_s[el * 132 + c0]) = o;
        }
        if (ch == 0) {
            // commit T registers -> LDS (f = r*256 + t; i = f>>5, k4 = (f&31)*4)
            int f;
            f = t;        *((float4*)&T_lds[(f >> 5) * 132 + (f & 31) * 4]) = tq0;
            f = t + 256;  *((float4*)&T_lds[(f >> 5) * 132 + (f & 31) * 4]) = tq1;
            f = t + 512;  *((float4*)&T_lds[(f >> 5) * 132 + (f & 31) * 4]) = tq2;
            f = t + 768;  *((float4*)&T_lds[(f >> 5) * 132 + (f & 31) * 4]) = tq3;
        }
        __syncthreads();
        // contraction (edge8 verbatim): thread (e_rel, i2)
        int idx = ch * 16 + e_rel;
        if (idx < dcount) {
            int e = perm[rstart + idx];                         // L2 broadcast
            int d = load_idx(ei, is64, (long long)nedges + e, nnodes);
            float a0 = u_lds[i2], a1 = u_lds[i2 + 16];
#pragma unroll
            for (int k4 = 0; k4 < 32; k4++) {
                float4 hv = *((const float4*)&hid_s[e_rel * 132 + k4 * 4]);
                float4 t0 = *((const float4*)&T_lds[i2 * 132 + k4 * 4]);
                float4 t1 = *((const float4*)&T_lds[(i2 + 16) * 132 + k4 * 4]);
                a0 += hv.x * t0.x + hv.y * t0.y + hv.z * t0.z + hv.w * t0.w;
                a1 += hv.x * t1.x + hv.y * t1.y + hv.z * t1.z + hv.w * t1.w;
            }
            atomicAdd(&agg[(size_t)d * H + i2], a0);
            atomicAdd(&agg[(size_t)d * H + i2 + 16], a1);
        }
    }
}

// ---- LO tier: R5's known-good direct VALU message kernel -----------------
__global__ __launch_bounds__(256) void k_msg_valu(
    const void* __restrict__ ea, const void* __restrict__ w1,
    const void* __restrict__ b1g, const void* __restrict__ w2g,
    const void* __restrict__ b2g, const float* __restrict__ h,
    const int* __restrict__ ei, const int* __restrict__ flags,
    float* __restrict__ agg, int nedges, int nnodes)
{
    __shared__ float hid_s[64 * 130];
    __shared__ float w1_s[ED * MH];
    __shared__ float b1_s[MH];
    __shared__ float ea_f[64 * ED];

    int t = threadIdx.x;
    int e0 = blockIdx.x * 64;
    int isf32 = flags[0], is64 = flags[1];

    for (int i = t; i < 64 * ED; i += 256) {
        int e = e0 + (i >> 4);
        ea_f[i] = (e < nedges) ? ldf(ea, (size_t)e * ED + (i & 15), isf32) : 0.f;
    }
    for (int i = t; i < ED * MH; i += 256) w1_s[i] = ldf(w1, i, isf32);
    for (int i = t; i < MH; i += 256) b1_s[i] = ldf(b1g, i, isf32);
    __syncthreads();

    for (int idx = t; idx < 64 * MH; idx += 256) {
        int el = idx >> 7, c = idx & 127;
        float acc = b1_s[c];
#pragma unroll
        for (int k = 0; k < ED; k++)
            acc += ea_f[el * ED + k] * w1_s[k * MH + c];
        hid_s[el * 130 + c] = fmaxf(acc, 0.f);
    }
    __syncthreads();

    int lane = t & 63, w = t >> 6;
    int b = w * 64 + lane;
    int j = b & 31;
    int q = b >> 5;

    float b2v[4];
#pragma unroll
    for (int m = 0; m < 4; m++) b2v[m] = ldf(b2g, b + 256 * m, isf32);

    for (int g = 0; g < 4; g++) {
        float acc[16][4];
#pragma unroll
        for (int e = 0; e < 16; e++)
#pragma unroll
            for (int m = 0; m < 4; m++) acc[e][m] = 0.f;

        for (int k2 = 0; k2 < 64; k2++) {
            float w2a[4], w2b[4];
#pragma unroll
            for (int m = 0; m < 4; m++) {
                w2a[m] = ldf(w2g, (size_t)(2 * k2) * HH + b + 256 * m, isf32);
                w2b[m] = ldf(w2g, (size_t)(2 * k2 + 1) * HH + b + 256 * m, isf32);
            }
#pragma unroll
            for (int e = 0; e < 16; e++) {
                float2 hv = *((const float2*)&hid_s[(g * 16 + e) * 130 + 2 * k2]);
#pragma unroll
                for (int m = 0; m < 4; m++)
                    acc[e][m] += hv.x * w2a[m] + hv.y * w2b[m];
            }
        }

#pragma unroll
        for (int e = 0; e < 16; e++) {
            int eg = e0 + g * 16 + e;
            int valid = (eg < nedges);
            int se = valid ? load_idx(ei, is64, eg, nnodes) : 0;
            float he = h[(size_t)se * H + j];
            int d = valid ? load_idx(ei, is64, (long long)nedges + eg, nnodes) : 0;
#pragma unroll
            for (int m = 0; m < 4; m++) {
                float p = (acc[e][m] + b2v[m]) * he;
                p += __shfl_xor(p, 1);
                p += __shfl_xor(p, 2);
                p += __shfl_xor(p, 4);
                p += __shfl_xor(p, 8);
                p += __shfl_xor(p, 16);
                if ((lane & 31) == 0 && valid)
                    atomicAdd(&agg[(size_t)d * H + (q + 8 * m)], p);
            }
        }
    }
}

// ---- K3: GRU cell; zeroes hin (next agg); fused u_next when emit_u -------
__global__ __launch_bounds__(256) void k_gru(
    const float* __restrict__ agg, float* hin,
    const void* __restrict__ w_ih, const void* __restrict__ w_hh,
    const void* __restrict__ b_ih, const void* __restrict__ b_hh,
    const void* __restrict__ b2g, float* __restrict__ u_next,
    float* __restrict__ hout, void* __restrict__ out_any,
    int nnodes, int finalstep, int emit_u, const int* __restrict__ flags)
{
    __shared__ float wih_s[3 * H][H + 1];
    __shared__ float whh_s[3 * H][H + 1];
    __shared__ float bih_s[3 * H], bhh_s[3 * H];
    __shared__ float a_s[8][H + 1], h_s[8][H + 1], hn_s[8][33];
    __shared__ float b2_s[32 * 33];
    int isf32 = flags[0];
    int t = threadIdx.x;
    for (int i = t; i < 3 * H * H; i += 256) {
        wih_s[i >> 5][i & 31] = ldf(w_ih, i, isf32);
        whh_s[i >> 5][i & 31] = ldf(w_hh, i, isf32);
    }
    for (int i = t; i < 3 * H; i += 256) {
        bih_s[i] = ldf(b_ih, i, isf32);
        bhh_s[i] = ldf(b_hh, i, isf32);
    }
    if (emit_u && !finalstep)
        for (int i = t; i < 1024; i += 256)
            b2_s[(i >> 5) * 33 + (i & 31)] = ldf(b2g, i, isf32);
    int nl = t >> 5, i = t & 31;
    int n = blockIdx.x * 8 + nl;
    int act = (n < nnodes);
    if (act) {
        a_s[nl][i] = agg[(size_t)n * H + i];
        h_s[nl][i] = hin[(size_t)n * H + i];
    }
    __syncthreads();

    if (act) {
        float gr = bih_s[i], gz = bih_s[H + i], gn = bih_s[2 * H + i];
        float hr = bhh_s[i], hz = bhh_s[H + i], hn = bhh_s[2 * H + i];
#pragma unroll
        for (int jj = 0; jj < H; jj++) {
            float a = a_s[nl][jj], hh = h_s[nl][jj];
            gr += a * wih_s[i][jj];      gz += a * wih_s[H + i][jj];  gn += a * wih_s[2 * H + i][jj];
            hr += hh * whh_s[i][jj];     hz += hh * whh_s[H + i][jj]; hn += hh * whh_s[2 * H + i][jj];
        }
        float r  = 1.f / (1.f + __expf(-(gr + hr)));
        float z  = 1.f / (1.f + __expf(-(gz + hz)));
        float nv = tanhf(gn + r * hn);
        float hnew = (1.f - z) * nv + z * h_s[nl][i];
        hout[(size_t)n * H + i] = hnew;
        hin[(size_t)n * H + i] = 0.f;        // pre-zero next step's agg
        hn_s[nl][i] = hnew;
        if (finalstep) {
            if (isf32) ((float*)out_any)[(size_t)n * H + i] = hnew;
            else       ((uint16_t*)out_any)[(size_t)n * H + i] = f2bf(hnew);
        }
    }
    if (emit_u && !finalstep) {
        __syncthreads();
        if (act) {
            float au = 0.f;
#pragma unroll
            for (int j = 0; j < 32; j++) au += b2_s[i * 33 + j] * hn_s[nl][j];
            u_next[(size_t)n * 32 + i] = au;
        }
    }
}

// ---- launch --------------------------------------------------------------
extern "C" void kernel_launch(void* const* d_in, const int* in_sizes, int n_in,
                              void* d_out, int out_size, void* d_ws, size_t ws_size,
                              hipStream_t stream)
{
    const void* x   = d_in[0];
    const int*  ei  = (const int*)d_in[1];
    const void* ea  = d_in[2];
    const void* wp  = d_in[3];
    const void* bp  = d_in[4];
    const void* w1  = d_in[5];
    const void* b1  = d_in[6];
    const void* w2  = d_in[7];
    const void* b2  = d_in[8];
    const void* wih = d_in[9];
    const void* whh = d_in[10];
    const void* bih = d_in[11];
    const void* bhh = d_in[12];

    int nnodes = in_sizes[0] / ND;       // 10000
    int nedges = in_sizes[1] / 2;        // 160000

    size_t hbytes = (size_t)nnodes * H * sizeof(float);          // 1.28 MB
    size_t tbytes = (size_t)nnodes * 4096 * sizeof(float);       // 163.84 MB
    if (ws_size < 256 + 2 * hbytes) return;   // absmax==max|ref| => ws too small

    size_t off = 0;
    int*   flags  = (int*)d_ws;                 off += 256;
    float* bufA   = (float*)((char*)d_ws + off); off += hbytes;
    float* bufB   = (float*)((char*)d_ws + off); off += hbytes;
    float* u_buf  = (float*)((char*)d_ws + off); off += hbytes;
    int*   deg    = (int*)((char*)d_ws + off);   off += (size_t)nnodes * 4;
    int*   cursor = (int*)((char*)d_ws + off);   off += (size_t)nnodes * 4;
    int*   perm   = (int*)((char*)d_ws + off);   off += (size_t)nedges * 4;
    off = (off + 255) & ~(size_t)255;
    float* Bperm  = (float*)((char*)d_ws + off); off += (size_t)MH * HH * 4;  // 512 KB
    float* w1f    = (float*)((char*)d_ws + off); off += (size_t)ED * MH * 4;  // 8 KB
    float* b1f    = (float*)((char*)d_ws + off); off += (size_t)MH * 4;       // 512 B
    off = (off + 255) & ~(size_t)255;
    float* Tall   = (float*)((char*)d_ws + off); off += tbytes;
    int hi_tier = (ws_size >= off);

    k_detect<<<1, 256, 0, stream>>>((const uint16_t*)x, ei, nedges, flags);
    k_node_proj<<<(nnodes + 7) / 8, 256, 0, stream>>>(
        x, wp, bp, b2, bufA, u_buf, nnodes, hi_tier, flags);
    hipMemsetAsync(bufB, 0, hbytes, stream);     // s=0 agg; later zeroed by k_gru

    if (hi_tier) {
        hipMemsetAsync(deg, 0, (size_t)nnodes * 4, stream);
        k_hist<<<(nedges + 255) / 256, 256, 0, stream>>>(ei, flags, deg, nedges, nnodes);
        k_scan<<<1, 256, 0, stream>>>(deg, cursor, nnodes);
        k_scatter<<<(nedges + 255) / 256, 256, 0, stream>>>(ei, flags, cursor, perm, nedges, nnodes);
        k_permw2<<<(MH * HH + 255) / 256, 256, 0, stream>>>(w2, Bperm, flags);
        k_prepw1<<<(ED * MH + 255) / 256, 256, 0, stream>>>(w1, b1, w1f, b1f, flags);
        // after k_scatter: cursor[n] == row end, deg[n] == row degree
    }

    float* hcur = bufA;
    float* aggb = bufB;
    for (int s = 0; s < 3; s++) {
        if (hi_tier) {
            k_T6<<<((nnodes + 127) / 128) * 8, 256, 0, stream>>>(
                Bperm, hcur, Tall, nnodes);
            k_edge9<<<nnodes, 256, 0, stream>>>(
                ea, w1f, b1f, Tall, u_buf, ei, perm, deg, cursor, flags,
                aggb, nedges, nnodes);
        } else {
            k_msg_valu<<<(nedges + 63) / 64, 256, 0, stream>>>(
                ea, w1, b1, w2, b2, hcur, ei, flags, aggb, nedges, nnodes);
        }
        k_gru<<<(nnodes + 7) / 8, 256, 0, stream>>>(
            aggb, hcur, wih, whh, bih, bhh, b2, u_buf, aggb, d_out,
            nnodes, s == 2, hi_tier, flags);
        float* tmp = hcur; hcur = aggb; aggb = tmp;
    }
}